// Round 1
// baseline (116.923 us; speedup 1.0000x reference)
//
#include <hip/hip_runtime.h>

#define NN   30000
#define NCTX 32
#define FIN  256
#define HID  128

__device__ __forceinline__ unsigned short f2b(float x) {
    union { float f; unsigned u; } v; v.f = x;
    unsigned r = v.u + 0x7FFFu + ((v.u >> 16) & 1u);   // round-to-nearest-even
    return (unsigned short)(r >> 16);
}
__device__ __forceinline__ float b2f(unsigned short u) {
    union { unsigned u; float f; } v; v.u = ((unsigned)u) << 16;
    return v.f;
}

// v_i[f] = sum_h W_i[f][h] * a_w[h]
__global__ void k_prep(const float* __restrict__ Wi, const float* __restrict__ aw,
                       float* __restrict__ vi) {
    const int f = threadIdx.x;
    float s = 0.f;
    #pragma unroll 8
    for (int h = 0; h < HID; ++h) s += Wi[f * HID + h] * aw[h];
    vi[f] = s;
}

// Wh = h_i @ W_j  (M=30000, N=128, K=256), stored bf16.
// 8 rows / block of 256 threads; thread = (col c, row-group rg of 4 rows).
__global__ __launch_bounds__(256) void k_gemm(const float* __restrict__ hin,
                                              const float* __restrict__ Wj,
                                              unsigned short* __restrict__ Wh) {
    __shared__ float hs[8 * FIN];
    const int tid = threadIdx.x;
    const long rbase = (long)blockIdx.x * 8;
    const float4* h4 = (const float4*)(hin + rbase * FIN);
    float4* s4 = (float4*)hs;
    s4[tid]        = h4[tid];
    s4[tid + 256]  = h4[tid + 256];
    __syncthreads();
    const int c  = tid & 127;
    const int rg = tid >> 7;
    const float* hr = hs + rg * (4 * FIN);
    float a0 = 0.f, a1 = 0.f, a2 = 0.f, a3 = 0.f;
    #pragma unroll 4
    for (int k = 0; k < FIN; k += 4) {
        const float w0 = Wj[(k + 0) * HID + c];
        const float w1 = Wj[(k + 1) * HID + c];
        const float w2 = Wj[(k + 2) * HID + c];
        const float w3 = Wj[(k + 3) * HID + c];
        const float4 h0 = *(const float4*)(hr + 0 * FIN + k);
        const float4 h1 = *(const float4*)(hr + 1 * FIN + k);
        const float4 h2 = *(const float4*)(hr + 2 * FIN + k);
        const float4 h3 = *(const float4*)(hr + 3 * FIN + k);
        a0 += h0.x * w0 + h0.y * w1 + h0.z * w2 + h0.w * w3;
        a1 += h1.x * w0 + h1.y * w1 + h1.z * w2 + h1.w * w3;
        a2 += h2.x * w0 + h2.y * w1 + h2.z * w2 + h2.w * w3;
        a3 += h3.x * w0 + h3.y * w1 + h3.z * w2 + h3.w * w3;
    }
    const long ob = (rbase + (long)rg * 4) * HID + c;
    Wh[ob + 0 * HID] = f2b(a0);
    Wh[ob + 1 * HID] = f2b(a1);
    Wh[ob + 2 * HID] = f2b(a2);
    Wh[ob + 3 * HID] = f2b(a3);
}

// si_b[n] = h_i[n].v_i + a_b ;  sj[n] = Wh[n].a_w[128:]
// one wave per node
__global__ __launch_bounds__(256) void k_scores(const float* __restrict__ hin,
                                                const unsigned short* __restrict__ Wh,
                                                const float* __restrict__ vi,
                                                const float* __restrict__ aw,
                                                const float* __restrict__ ab,
                                                float* __restrict__ sib,
                                                float* __restrict__ sjv) {
    const int lane = threadIdx.x & 63;
    const long n = (long)blockIdx.x * 4 + (threadIdx.x >> 6);
    const float4 hv = ((const float4*)(hin + n * FIN))[lane];
    const float4 vv = ((const float4*)vi)[lane];
    float si = hv.x * vv.x + hv.y * vv.y + hv.z * vv.z + hv.w * vv.w;
    const unsigned pv = ((const unsigned*)(Wh + n * HID))[lane];
    float sj = b2f((unsigned short)(pv & 0xFFFFu)) * aw[HID + 2 * lane]
             + b2f((unsigned short)(pv >> 16))     * aw[HID + 2 * lane + 1];
    #pragma unroll
    for (int m = 32; m >= 1; m >>= 1) {
        si += __shfl_xor(si, m);
        sj += __shfl_xor(sj, m);
    }
    if (lane == 0) { sib[n] = si + ab[0]; sjv[n] = sj; }
}

// per-node: scores -> leakyrelu -> mask -> softmax -> h' = sum attn_c * Wh[idx_c]
// one wave per node; lanes 0..31 own context slots (mirrored in 32..63)
__global__ __launch_bounds__(256) void k_attn(const int* __restrict__ ctx,
                                              const unsigned short* __restrict__ Wh,
                                              const float* __restrict__ sib,
                                              const float* __restrict__ sjv,
                                              float* __restrict__ out) {
    const int lane = threadIdx.x & 63;
    const long n = (long)blockIdx.x * 4 + (threadIdx.x >> 6);
    const int c = lane & 31;
    const int idx = ctx[n * NCTX + c];
    float s;
    if (idx >= 0) {
        s = sib[n] + sjv[idx];
        s = (s >= 0.f) ? s : 0.2f * s;
    } else {
        s = -9e15f;
    }
    // max over the 32 slots (halves of the wave hold identical values)
    float mx = s;
    #pragma unroll
    for (int m = 16; m >= 1; m >>= 1) mx = fmaxf(mx, __shfl_xor(mx, m));
    const float e = __expf(s - mx);
    float sum = e;
    #pragma unroll
    for (int m = 16; m >= 1; m >>= 1) sum += __shfl_xor(sum, m);
    const float at = e / sum;

    float2 acc = {0.f, 0.f};
    #pragma unroll 4
    for (int cc = 0; cc < 32; ++cc) {
        const float w  = __shfl(at, cc);
        const int   ic = __shfl(idx, cc);
        if (ic >= 0) {
            const unsigned pv = ((const unsigned*)(Wh + (long)ic * HID))[lane];
            acc.x += w * b2f((unsigned short)(pv & 0xFFFFu));
            acc.y += w * b2f((unsigned short)(pv >> 16));
        }
    }
    ((float2*)out)[n * 64 + lane] = acc;
}

extern "C" void kernel_launch(void* const* d_in, const int* in_sizes, int n_in,
                              void* d_out, int out_size, void* d_ws, size_t ws_size,
                              hipStream_t stream) {
    const float* h_i = (const float*)d_in[0];
    const int*   ctx = (const int*)d_in[1];
    const float* W_i = (const float*)d_in[2];
    const float* W_j = (const float*)d_in[3];
    const float* a_w = (const float*)d_in[4];
    const float* a_b = (const float*)d_in[5];
    float* out = (float*)d_out;

    char* ws = (char*)d_ws;
    unsigned short* Wh = (unsigned short*)ws;           // N*H bf16 = 7,680,000 B
    float* sib = (float*)(ws + 7680000);                // N f32
    float* sjv = (float*)(ws + 7800000);                // N f32
    float* vi  = (float*)(ws + 7920000);                // 256 f32

    k_prep  <<<1, 256, 0, stream>>>(W_i, a_w, vi);
    k_gemm  <<<NN / 8, 256, 0, stream>>>(h_i, W_j, Wh);
    k_scores<<<NN / 4, 256, 0, stream>>>(h_i, Wh, vi, a_w, a_b, sib, sjv);
    k_attn  <<<NN / 4, 256, 0, stream>>>(ctx, Wh, sib, sjv, out);
}

// Round 2
// 92.378 us; speedup vs baseline: 1.2657x; 1.2657x over previous
//
#include <hip/hip_runtime.h>

#define NN   30000
#define NCTX 32
#define FIN  256
#define HID  128

typedef short short8 __attribute__((ext_vector_type(8)));
typedef float f32x4  __attribute__((ext_vector_type(4)));

__device__ __forceinline__ unsigned short f2b(float x) {
    union { float f; unsigned u; } v; v.f = x;
    unsigned r = v.u + 0x7FFFu + ((v.u >> 16) & 1u);   // RTNE
    return (unsigned short)(r >> 16);
}
__device__ __forceinline__ float b2f(unsigned short u) {
    union { unsigned u; float f; } v; v.u = ((unsigned)u) << 16;
    return v.f;
}

// v_i[f] = sum_h W_i[f][h] * a_w[h]
__global__ void k_prep(const float* __restrict__ Wi, const float* __restrict__ aw,
                       float* __restrict__ vi) {
    const int f = threadIdx.x;
    float s = 0.f;
    #pragma unroll 8
    for (int h = 0; h < HID; ++h) s += Wi[f * HID + h] * aw[h];
    vi[f] = s;
}

// Pack W_j into MFMA B-fragment order, split bf16 hi/lo.
// Block b = (s*8+t): k-step s, col-tile t. Lane l holds B[k=s*32+(l>>4)*8+j][c=t*16+(l&15)].
__global__ __launch_bounds__(64) void k_pack(const float* __restrict__ Wj,
                                             short8* __restrict__ whi,
                                             short8* __restrict__ wlo) {
    const int b = blockIdx.x;
    const int l = threadIdx.x;
    const int s = b >> 3, t = b & 7;
    const int kbase = s * 32 + (l >> 4) * 8;
    const int c = t * 16 + (l & 15);
    short8 hi, lo;
    #pragma unroll
    for (int j = 0; j < 8; ++j) {
        const float w = Wj[(long)(kbase + j) * HID + c];
        const unsigned short h = f2b(w);
        hi[j] = (short)h;
        lo[j] = (short)f2b(w - b2f(h));
    }
    whi[b * 64 + l] = hi;
    wlo[b * 64 + l] = lo;
}

// Fused: Wh = h_i @ W_j (MFMA, split-bf16), si = h_i.vi + ab, sj = Wh.a_w[128:]
// One wave per 16 rows. 4 waves/block, no LDS, no barriers.
__global__ __launch_bounds__(256) void k_gemm(const float* __restrict__ hin,
                                              const short8* __restrict__ whi,
                                              const short8* __restrict__ wlo,
                                              const float* __restrict__ vi,
                                              const float* __restrict__ aw,
                                              const float* __restrict__ ab,
                                              unsigned short* __restrict__ Wh,
                                              float* __restrict__ sib,
                                              float* __restrict__ sjv) {
    const int tid  = threadIdx.x;
    const int l    = tid & 63;
    const int wave = blockIdx.x * 4 + (tid >> 6);
    if (wave >= NN / 16) return;
    const long rowbase = (long)wave * 16;
    const int r  = l & 15;    // A row / D col-within-tile
    const int kg = l >> 4;    // k-group

    const float* hrow = hin + (rowbase + r) * FIN + kg * 8;
    const float* vip  = vi + kg * 8;

    f32x4 acc[8];
    #pragma unroll
    for (int t = 0; t < 8; ++t) acc[t] = (f32x4){0.f, 0.f, 0.f, 0.f};
    float si = 0.f;

    #pragma unroll 2
    for (int s = 0; s < 8; ++s) {
        const float4 ha = *(const float4*)(hrow + s * 32);
        const float4 hb = *(const float4*)(hrow + s * 32 + 4);
        const float4 va = *(const float4*)(vip + s * 32);
        const float4 vb = *(const float4*)(vip + s * 32 + 4);
        const float hv[8] = {ha.x, ha.y, ha.z, ha.w, hb.x, hb.y, hb.z, hb.w};
        const float vv[8] = {va.x, va.y, va.z, va.w, vb.x, vb.y, vb.z, vb.w};
        short8 ahi, alo;
        #pragma unroll
        for (int j = 0; j < 8; ++j) {
            si += hv[j] * vv[j];
            const unsigned short hb16 = f2b(hv[j]);
            ahi[j] = (short)hb16;
            alo[j] = (short)f2b(hv[j] - b2f(hb16));
        }
        #pragma unroll
        for (int t = 0; t < 8; ++t) {
            const short8 bh = whi[(s * 8 + t) * 64 + l];
            const short8 bl = wlo[(s * 8 + t) * 64 + l];
            acc[t] = __builtin_amdgcn_mfma_f32_16x16x32_bf16(ahi, bh, acc[t], 0, 0, 0);
            acc[t] = __builtin_amdgcn_mfma_f32_16x16x32_bf16(alo, bh, acc[t], 0, 0, 0);
            acc[t] = __builtin_amdgcn_mfma_f32_16x16x32_bf16(ahi, bl, acc[t], 0, 0, 0);
        }
    }

    // si: lane holds partial for row r over k in {s*32+kg*8..+7}; reduce over kg (bits 4,5)
    si += __shfl_xor(si, 16);
    si += __shfl_xor(si, 32);
    if (l < 16) sib[rowbase + l] = si + ab[0];

    // sj[row] from f32 accumulator: p[j] = sum_t acc[t][j]*aw2[t*16+r], reduce over r (bits 0..3)
    float aw2v[8];
    #pragma unroll
    for (int t = 0; t < 8; ++t) aw2v[t] = aw[HID + t * 16 + r];
    #pragma unroll
    for (int j = 0; j < 4; ++j) {
        float p = 0.f;
        #pragma unroll
        for (int t = 0; t < 8; ++t) p += acc[t][j] * aw2v[t];
        p += __shfl_xor(p, 1); p += __shfl_xor(p, 2);
        p += __shfl_xor(p, 4); p += __shfl_xor(p, 8);
        if (r == 0) sjv[rowbase + kg * 4 + j] = p;
    }

    // store Wh bf16: D row = kg*4+j, col = t*16+r
    #pragma unroll
    for (int j = 0; j < 4; ++j) {
        const long rr = rowbase + kg * 4 + j;
        #pragma unroll
        for (int t = 0; t < 8; ++t)
            Wh[rr * HID + t * 16 + r] = f2b(acc[t][j]);
    }
}

// per-node: scores -> leakyrelu -> mask -> softmax -> h' = sum attn_c * Wh[idx_c]
__global__ __launch_bounds__(256) void k_attn(const int* __restrict__ ctx,
                                              const unsigned short* __restrict__ Wh,
                                              const float* __restrict__ sib,
                                              const float* __restrict__ sjv,
                                              float* __restrict__ out) {
    const int lane = threadIdx.x & 63;
    const long n = (long)blockIdx.x * 4 + (threadIdx.x >> 6);
    const int c = lane & 31;
    const int idx = ctx[n * NCTX + c];
    float s;
    if (idx >= 0) {
        s = sib[n] + sjv[idx];
        s = (s >= 0.f) ? s : 0.2f * s;
    } else {
        s = -9e15f;
    }
    float mx = s;
    #pragma unroll
    for (int m = 16; m >= 1; m >>= 1) mx = fmaxf(mx, __shfl_xor(mx, m));
    const float e = __expf(s - mx);
    float sum = e;
    #pragma unroll
    for (int m = 16; m >= 1; m >>= 1) sum += __shfl_xor(sum, m);
    const float at = e / sum;

    float2 acc = {0.f, 0.f};
    #pragma unroll 4
    for (int cc = 0; cc < 32; ++cc) {
        const float w  = __shfl(at, cc);
        const int   ic = __shfl(idx, cc);
        if (ic >= 0) {
            const unsigned pv = ((const unsigned*)(Wh + (long)ic * HID))[lane];
            acc.x += w * b2f((unsigned short)(pv & 0xFFFFu));
            acc.y += w * b2f((unsigned short)(pv >> 16));
        }
    }
    ((float2*)out)[n * 64 + lane] = acc;
}

extern "C" void kernel_launch(void* const* d_in, const int* in_sizes, int n_in,
                              void* d_out, int out_size, void* d_ws, size_t ws_size,
                              hipStream_t stream) {
    const float* h_i = (const float*)d_in[0];
    const int*   ctx = (const int*)d_in[1];
    const float* W_i = (const float*)d_in[2];
    const float* W_j = (const float*)d_in[3];
    const float* a_w = (const float*)d_in[4];
    const float* a_b = (const float*)d_in[5];
    float* out = (float*)d_out;

    char* ws = (char*)d_ws;
    unsigned short* Wh = (unsigned short*)ws;           // N*H bf16 = 7,680,000 B
    float* sib = (float*)(ws + 7680000);                // N f32
    float* sjv = (float*)(ws + 7800000);                // N f32
    float* vi  = (float*)(ws + 7920000);                // 256 f32 (16B aligned)
    short8* whi = (short8*)(ws + 7921024);              // 64 KB, 16B aligned
    short8* wlo = (short8*)(ws + 7986560);              // 64 KB, 16B aligned

    k_prep<<<1, 256, 0, stream>>>(W_i, a_w, vi);
    k_pack<<<64, 64, 0, stream>>>(W_j, whi, wlo);
    k_gemm<<<(NN / 16 + 3) / 4, 256, 0, stream>>>(h_i, whi, wlo, vi, a_w, a_b, Wh, sib, sjv);
    k_attn<<<NN / 4, 256, 0, stream>>>(ctx, Wh, sib, sjv, out);
}

// Round 3
// 69.528 us; speedup vs baseline: 1.6817x; 1.3286x over previous
//
#include <hip/hip_runtime.h>

#define NN   30000
#define NCTX 32
#define FIN  256
#define HID  128

typedef short short8 __attribute__((ext_vector_type(8)));
typedef float f32x4  __attribute__((ext_vector_type(4)));

__device__ __forceinline__ unsigned short f2b(float x) {
    union { float f; unsigned u; } v; v.f = x;
    unsigned r = v.u + 0x7FFFu + ((v.u >> 16) & 1u);   // RTNE
    return (unsigned short)(r >> 16);
}
__device__ __forceinline__ float b2f(unsigned short u) {
    union { unsigned u; float f; } v; v.u = ((unsigned)u) << 16;
    return v.f;
}

// Pack W_j into MFMA B-fragment order (split bf16 hi/lo); block 64 computes
// vi[f] = sum_h W_i[f][h]*a_w[h].
__global__ __launch_bounds__(64) void k_pack(const float* __restrict__ Wj,
                                             const float* __restrict__ Wi,
                                             const float* __restrict__ aw,
                                             short8* __restrict__ whi,
                                             short8* __restrict__ wlo,
                                             float* __restrict__ vi) {
    const int b = blockIdx.x;
    const int l = threadIdx.x;
    if (b == 64) {
        #pragma unroll
        for (int i = 0; i < 4; ++i) {
            const int f = l * 4 + i;
            float s = 0.f;
            #pragma unroll 8
            for (int h = 0; h < HID; ++h) s += Wi[f * HID + h] * aw[h];
            vi[f] = s;
        }
        return;
    }
    const int s = b >> 3, t = b & 7;
    const int kbase = s * 32 + (l >> 4) * 8;
    const int c = t * 16 + (l & 15);
    short8 hi, lo;
    #pragma unroll
    for (int j = 0; j < 8; ++j) {
        const float w = Wj[(long)(kbase + j) * HID + c];
        const unsigned short h = f2b(w);
        hi[j] = (short)h;
        lo[j] = (short)f2b(w - b2f(h));
    }
    whi[b * 64 + l] = hi;
    wlo[b * 64 + l] = lo;
}

// Fused: Wh = h_i @ W_j (MFMA, split-bf16), si = h_i.vi + ab, sj = Wh.a_w[128:]
__global__ __launch_bounds__(256) void k_gemm(const float* __restrict__ hin,
                                              const short8* __restrict__ whi,
                                              const short8* __restrict__ wlo,
                                              const float* __restrict__ vi,
                                              const float* __restrict__ aw,
                                              const float* __restrict__ ab,
                                              unsigned short* __restrict__ Wh,
                                              float* __restrict__ sib,
                                              float* __restrict__ sjv) {
    const int tid  = threadIdx.x;
    const int l    = tid & 63;
    const int wave = blockIdx.x * 4 + (tid >> 6);
    if (wave >= NN / 16) return;
    const long rowbase = (long)wave * 16;
    const int r  = l & 15;    // A row / D col-within-tile
    const int kg = l >> 4;    // k-group

    const float* hrow = hin + (rowbase + r) * FIN + kg * 8;
    const float* vip  = vi + kg * 8;

    f32x4 acc[8];
    #pragma unroll
    for (int t = 0; t < 8; ++t) acc[t] = (f32x4){0.f, 0.f, 0.f, 0.f};
    float si = 0.f;

    #pragma unroll 2
    for (int s = 0; s < 8; ++s) {
        const float4 ha = *(const float4*)(hrow + s * 32);
        const float4 hb = *(const float4*)(hrow + s * 32 + 4);
        const float4 va = *(const float4*)(vip + s * 32);
        const float4 vb = *(const float4*)(vip + s * 32 + 4);
        const float hv[8] = {ha.x, ha.y, ha.z, ha.w, hb.x, hb.y, hb.z, hb.w};
        const float vv[8] = {va.x, va.y, va.z, va.w, vb.x, vb.y, vb.z, vb.w};
        short8 ahi, alo;
        #pragma unroll
        for (int j = 0; j < 8; ++j) {
            si += hv[j] * vv[j];
            const unsigned short hb16 = f2b(hv[j]);
            ahi[j] = (short)hb16;
            alo[j] = (short)f2b(hv[j] - b2f(hb16));
        }
        #pragma unroll
        for (int t = 0; t < 8; ++t) {
            const short8 bh = whi[(s * 8 + t) * 64 + l];
            const short8 bl = wlo[(s * 8 + t) * 64 + l];
            acc[t] = __builtin_amdgcn_mfma_f32_16x16x32_bf16(ahi, bh, acc[t], 0, 0, 0);
            acc[t] = __builtin_amdgcn_mfma_f32_16x16x32_bf16(alo, bh, acc[t], 0, 0, 0);
            acc[t] = __builtin_amdgcn_mfma_f32_16x16x32_bf16(ahi, bl, acc[t], 0, 0, 0);
        }
    }

    si += __shfl_xor(si, 16);
    si += __shfl_xor(si, 32);
    if (l < 16) sib[rowbase + l] = si + ab[0];

    float aw2v[8];
    #pragma unroll
    for (int t = 0; t < 8; ++t) aw2v[t] = aw[HID + t * 16 + r];
    #pragma unroll
    for (int j = 0; j < 4; ++j) {
        float p = 0.f;
        #pragma unroll
        for (int t = 0; t < 8; ++t) p += acc[t][j] * aw2v[t];
        p += __shfl_xor(p, 1); p += __shfl_xor(p, 2);
        p += __shfl_xor(p, 4); p += __shfl_xor(p, 8);
        if (r == 0) sjv[rowbase + kg * 4 + j] = p;
    }

    #pragma unroll
    for (int j = 0; j < 4; ++j) {
        const long rr = rowbase + kg * 4 + j;
        #pragma unroll
        for (int t = 0; t < 8; ++t)
            Wh[rr * HID + t * 16 + r] = f2b(acc[t][j]);
    }
}

// per-node softmax + gather-aggregate. One wave per node.
// Gather: quarter-wave per row, 16B/lane -> 4 rows per load instruction,
// 8 independent wide loads in flight, no divergence in the loop.
__global__ __launch_bounds__(256) void k_attn(const int* __restrict__ ctx,
                                              const unsigned short* __restrict__ Wh,
                                              const float* __restrict__ sib,
                                              const float* __restrict__ sjv,
                                              float* __restrict__ out) {
    const int lane = threadIdx.x & 63;
    const long n = (long)blockIdx.x * 4 + (threadIdx.x >> 6);
    const int c = lane & 31;
    const int idx = ctx[n * NCTX + c];
    const int icl = (idx >= 0) ? idx : 0;
    float s;
    if (idx >= 0) {
        s = sib[n] + sjv[icl];
        s = (s >= 0.f) ? s : 0.2f * s;
    } else {
        s = -9e15f;
    }
    float mx = s;
    #pragma unroll
    for (int m = 16; m >= 1; m >>= 1) mx = fmaxf(mx, __shfl_xor(mx, m));
    const float e = __expf(s - mx);
    float sum = e;
    #pragma unroll
    for (int m = 16; m >= 1; m >>= 1) sum += __shfl_xor(sum, m);
    const float at = (idx >= 0) ? e / sum : 0.f;

    const int q  = lane >> 4;    // quarter: which row within the 4-row group
    const int cl = lane & 15;    // 16B column chunk

    float a0 = 0.f, a1 = 0.f, a2 = 0.f, a3 = 0.f, a4 = 0.f, a5 = 0.f, a6 = 0.f, a7 = 0.f;
    #pragma unroll
    for (int it = 0; it < 8; ++it) {
        const int   src = it * 4 + q;
        const float w   = __shfl(at, src);
        const int   ic  = __shfl(icl, src);
        const uint4 pv  = *(const uint4*)(Wh + (long)ic * HID + cl * 8);
        a0 += w * b2f((unsigned short)(pv.x & 0xFFFFu));
        a1 += w * b2f((unsigned short)(pv.x >> 16));
        a2 += w * b2f((unsigned short)(pv.y & 0xFFFFu));
        a3 += w * b2f((unsigned short)(pv.y >> 16));
        a4 += w * b2f((unsigned short)(pv.z & 0xFFFFu));
        a5 += w * b2f((unsigned short)(pv.z >> 16));
        a6 += w * b2f((unsigned short)(pv.w & 0xFFFFu));
        a7 += w * b2f((unsigned short)(pv.w >> 16));
    }
    #pragma unroll
    for (int m = 16; m <= 32; m <<= 1) {
        a0 += __shfl_xor(a0, m); a1 += __shfl_xor(a1, m);
        a2 += __shfl_xor(a2, m); a3 += __shfl_xor(a3, m);
        a4 += __shfl_xor(a4, m); a5 += __shfl_xor(a5, m);
        a6 += __shfl_xor(a6, m); a7 += __shfl_xor(a7, m);
    }
    if (lane < 16) {
        float4* op = (float4*)(out + n * HID + cl * 8);
        op[0] = (float4){a0, a1, a2, a3};
        op[1] = (float4){a4, a5, a6, a7};
    }
}

extern "C" void kernel_launch(void* const* d_in, const int* in_sizes, int n_in,
                              void* d_out, int out_size, void* d_ws, size_t ws_size,
                              hipStream_t stream) {
    const float* h_i = (const float*)d_in[0];
    const int*   ctx = (const int*)d_in[1];
    const float* W_i = (const float*)d_in[2];
    const float* W_j = (const float*)d_in[3];
    const float* a_w = (const float*)d_in[4];
    const float* a_b = (const float*)d_in[5];
    float* out = (float*)d_out;

    char* ws = (char*)d_ws;
    unsigned short* Wh = (unsigned short*)ws;           // N*H bf16 = 7,680,000 B
    float* sib = (float*)(ws + 7680000);                // N f32
    float* sjv = (float*)(ws + 7800000);                // N f32
    float* vi  = (float*)(ws + 7920000);                // 256 f32 (16B aligned)
    short8* whi = (short8*)(ws + 7921024);              // 64 KB
    short8* wlo = (short8*)(ws + 7986560);              // 64 KB

    k_pack<<<65, 64, 0, stream>>>(W_j, W_i, a_w, whi, wlo, vi);
    k_gemm<<<(NN / 16 + 3) / 4, 256, 0, stream>>>(h_i, whi, wlo, vi, a_w, a_b, Wh, sib, sjv);
    k_attn<<<NN / 4, 256, 0, stream>>>(ctx, Wh, sib, sjv, out);
}